// Round 6
// baseline (3801.973 us; speedup 1.0000x reference)
//
#include <hip/hip_runtime.h>
#include <hip/hip_bf16.h>
#include <math.h>

typedef float f32x4 __attribute__((ext_vector_type(4)));
typedef __bf16 bf16x4 __attribute__((ext_vector_type(4)));
typedef __bf16 bf16x8 __attribute__((ext_vector_type(8)));

#define AS1(p) ((const __attribute__((address_space(1))) void*)(p))
#define AS3(p) ((__attribute__((address_space(3))) void*)(p))

static constexpr int D_MODEL = 1024;
static constexpr int S_LEN   = 2048;
static constexpr int BATCH   = 4;
static constexpr int NTOK    = BATCH * S_LEN;   // 8192
static constexpr int NH      = 8;
static constexpr int DH      = 32;
static constexpr int NA      = NH * DH * DH;    // 8192
static constexpr int D_FF    = 4096;
static constexpr int CHUNK   = 16;
static constexpr int NCHUNK  = S_LEN / CHUNK;   // 128

// ---------------------------------------------------------------------------
// Transpose fp32 [R][C] -> bf16 [C][R]
// ---------------------------------------------------------------------------
__global__ __launch_bounds__(256) void transpose_bf16(
    const float* __restrict__ in, __bf16* __restrict__ out, int R, int C) {
  __shared__ float tile[32][33];
  int tx = threadIdx.x & 31, ty = threadIdx.x >> 5;   // 32 x 8
  int c0 = blockIdx.x * 32, r0 = blockIdx.y * 32;
  for (int i = ty; i < 32; i += 8)
    tile[i][tx] = in[(size_t)(r0 + i) * C + c0 + tx];
  __syncthreads();
  for (int i = ty; i < 32; i += 8)
    out[(size_t)(c0 + i) * R + r0 + tx] = (__bf16)tile[tx][i];
}

// ---------------------------------------------------------------------------
// LayerNorm row kernel: fp32 [NTOK][1024] -> bf16 or fp32
// ---------------------------------------------------------------------------
template <int F32OUT>
__global__ __launch_bounds__(256) void ln_kernel(
    const float* __restrict__ in, const float* __restrict__ g,
    const float* __restrict__ bta, void* __restrict__ outv) {
  int row = blockIdx.x, tid = threadIdx.x;
  const float4* in4 = (const float4*)(in + (size_t)row * D_MODEL);
  float4 v = in4[tid];
  float s  = v.x + v.y + v.z + v.w;
  float ss = v.x * v.x + v.y * v.y + v.z * v.z + v.w * v.w;
  for (int o = 32; o; o >>= 1) { s += __shfl_down(s, o); ss += __shfl_down(ss, o); }
  __shared__ float ps[4], pq[4];
  int lane = tid & 63, w = tid >> 6;
  if (lane == 0) { ps[w] = s; pq[w] = ss; }
  __syncthreads();
  s  = ps[0] + ps[1] + ps[2] + ps[3];
  ss = pq[0] + pq[1] + pq[2] + pq[3];
  float mean = s * (1.0f / D_MODEL);
  float var  = ss * (1.0f / D_MODEL) - mean * mean;
  float inv  = rsqrtf(fmaxf(var, 0.0f) + 1e-5f);
  float4 gv = ((const float4*)g)[tid];
  float4 bv = ((const float4*)bta)[tid];
  float o0 = (v.x - mean) * inv * gv.x + bv.x;
  float o1 = (v.y - mean) * inv * gv.y + bv.y;
  float o2 = (v.z - mean) * inv * gv.z + bv.z;
  float o3 = (v.w - mean) * inv * gv.w + bv.w;
  if (F32OUT) {
    float4 o = {o0, o1, o2, o3};
    ((float4*)outv)[(size_t)row * (D_MODEL / 4) + tid] = o;
  } else {
    bf16x4 o;
    o[0] = (__bf16)o0; o[1] = (__bf16)o1; o[2] = (__bf16)o2; o[3] = (__bf16)o3;
    ((bf16x4*)outv)[(size_t)row * (D_MODEL / 4) + tid] = o;
  }
}

// ---------------------------------------------------------------------------
// fp32 GEMM: out_f32[M][N] = A_f32[M][K] @ B_f32[K][N] + bias.
// B native row-major. LDS 64x64 tile, BK=16. Correct-first; MFMA-split later.
// ---------------------------------------------------------------------------
__global__ __launch_bounds__(256) void gemm_f32_f32out(
    const float* __restrict__ A, const float* __restrict__ B,
    const float* __restrict__ bias, float* __restrict__ out,
    int M, int N, int K) {
  __shared__ float As[16][65];
  __shared__ float Bs[16][65];
  int tid = threadIdx.x;
  int m0 = blockIdx.y * 64, n0 = blockIdx.x * 64;
  int tx = tid & 15, ty = tid >> 4;
  int lr = tid & 63, lg = tid >> 6;
  float acc[4][4];
#pragma unroll
  for (int u = 0; u < 4; u++)
#pragma unroll
    for (int v = 0; v < 4; v++) acc[u][v] = 0.0f;

  for (int k0 = 0; k0 < K; k0 += 16) {
    float4 av = *(const float4*)(A + (size_t)(m0 + lr) * K + k0 + lg * 4);
    As[lg * 4 + 0][lr] = av.x;
    As[lg * 4 + 1][lr] = av.y;
    As[lg * 4 + 2][lr] = av.z;
    As[lg * 4 + 3][lr] = av.w;
#pragma unroll
    for (int u = 0; u < 4; u++) {
      int kk = lg + u * 4;
      Bs[kk][lr] = B[(size_t)(k0 + kk) * N + n0 + lr];
    }
    __syncthreads();
#pragma unroll
    for (int kk = 0; kk < 16; kk++) {
      float a[4], b[4];
#pragma unroll
      for (int u = 0; u < 4; u++) a[u] = As[kk][ty * 4 + u];
#pragma unroll
      for (int v = 0; v < 4; v++) b[v] = Bs[kk][tx * 4 + v];
#pragma unroll
      for (int u = 0; u < 4; u++)
#pragma unroll
        for (int v = 0; v < 4; v++) acc[u][v] += a[u] * b[v];
    }
    __syncthreads();
  }
#pragma unroll
  for (int u = 0; u < 4; u++) {
    int row = m0 + ty * 4 + u;
#pragma unroll
    for (int v = 0; v < 4; v++) {
      int col = n0 + tx * 4 + v;
      out[(size_t)row * N + col] = acc[u][v] + bias[col];
    }
  }
}

// ---------------------------------------------------------------------------
// bf16 MFMA GEMM, m97 structure (unchanged, known-good for Wo/FFN)
// ---------------------------------------------------------------------------
enum { EPI_BF16_BIAS = 0, EPI_BF16_BIAS_GELU = 1, EPI_F32_BIAS_RES = 2 };

template <int EPI>
__global__ __launch_bounds__(256) void gemm_bf16(
    const __bf16* __restrict__ Amat, const __bf16* __restrict__ BT,
    const float* __restrict__ bias, const float* __restrict__ res,
    void* __restrict__ out, int M, int N, int K) {
  __shared__ __bf16 As[128 * 32];
  __shared__ __bf16 Bs[128 * 32];
  const int tid = threadIdx.x;
  const int lane = tid & 63, w = tid >> 6;
  const int m0 = blockIdx.y * 128, n0 = blockIdx.x * 128;
  const int wm = (w >> 1) * 64, wn = (w & 1) * 64;

  f32x4 acc[4][4];
#pragma unroll
  for (int a = 0; a < 4; a++)
#pragma unroll
    for (int b = 0; b < 4; b++)
#pragma unroll
      for (int r = 0; r < 4; r++) acc[a][b][r] = 0.0f;

  const int srow = tid >> 2;
  const int soff = (tid & 3) * 16;
  const __bf16* gA0 = Amat + (size_t)(m0 + srow) * K + (soff >> 1);
  const __bf16* gA1 = Amat + (size_t)(m0 + srow + 64) * K + (soff >> 1);
  const __bf16* gB0 = BT + (size_t)(n0 + srow) * K + (soff >> 1);
  const __bf16* gB1 = BT + (size_t)(n0 + srow + 64) * K + (soff >> 1);
  char* lA0 = (char*)As + srow * 64 + soff;
  char* lA1 = (char*)As + (srow + 64) * 64 + soff;
  char* lB0 = (char*)Bs + srow * 64 + soff;
  char* lB1 = (char*)Bs + (srow + 64) * 64 + soff;

  const int fm = lane & 15, fq = lane >> 4;
  for (int k0 = 0; k0 < K; k0 += 32) {
    __builtin_amdgcn_global_load_lds(AS1(gA0 + k0), AS3(lA0), 16, 0, 0);
    __builtin_amdgcn_global_load_lds(AS1(gA1 + k0), AS3(lA1), 16, 0, 0);
    __builtin_amdgcn_global_load_lds(AS1(gB0 + k0), AS3(lB0), 16, 0, 0);
    __builtin_amdgcn_global_load_lds(AS1(gB1 + k0), AS3(lB1), 16, 0, 0);
    __syncthreads();
    bf16x8 af[4], bf[4];
#pragma unroll
    for (int t = 0; t < 4; t++)
      af[t] = *(const bf16x8*)((const char*)As + (wm + t * 16 + fm) * 64 + fq * 16);
#pragma unroll
    for (int t = 0; t < 4; t++)
      bf[t] = *(const bf16x8*)((const char*)Bs + (wn + t * 16 + fm) * 64 + fq * 16);
#pragma unroll
    for (int tm = 0; tm < 4; tm++)
#pragma unroll
      for (int tn = 0; tn < 4; tn++)
        acc[tm][tn] = __builtin_amdgcn_mfma_f32_16x16x32_bf16(af[tm], bf[tn], acc[tm][tn], 0, 0, 0);
    __syncthreads();
  }

#pragma unroll
  for (int tn = 0; tn < 4; tn++) {
    int col = n0 + wn + tn * 16 + fm;
    float bv = bias[col];
#pragma unroll
    for (int tm = 0; tm < 4; tm++) {
#pragma unroll
      for (int r = 0; r < 4; r++) {
        int row = m0 + wm + tm * 16 + fq * 4 + r;
        float v = acc[tm][tn][r] + bv;
        size_t idx = (size_t)row * N + col;
        if (EPI == EPI_F32_BIAS_RES) {
          ((float*)out)[idx] = v + res[idx];
        } else if (EPI == EPI_BF16_BIAS_GELU) {
          v = 0.5f * v * (1.0f + erff(v * 0.70710678118654752f));
          ((__bf16*)out)[idx] = (__bf16)v;
        } else {
          ((__bf16*)out)[idx] = (__bf16)v;
        }
      }
    }
  }
}

// ---------------------------------------------------------------------------
// Phase 1 (per batch b): chunk product P = A_{s0+15}...A_{s0}, fp32 A in.
// Structure bit-identity-verified vs naive (r3==r4).
// ---------------------------------------------------------------------------
__global__ __launch_bounds__(64) void mps_chunkprod_f32(
    const float* __restrict__ A, float* __restrict__ P) {
  int bid = blockIdx.x;            // hh*128 + c
  int c = bid & 127, hh = bid >> 7;
  int lane = threadIdx.x;
  int i = lane & 31, half = lane >> 5;
  __shared__ float Al[32 * 33];
  __shared__ float cur[32 * 33];

  for (int j = 0; j < 16; j++)
    cur[i * 33 + half * 16 + j] = (i == half * 16 + j) ? 1.0f : 0.0f;
  __syncthreads();

  const float* Abase = A + (size_t)(c * CHUNK) * NA + (size_t)hh * (DH * DH);
  float nxt[16];
  for (int t = 0; t < CHUNK; t++) {
    const float* At = Abase + (size_t)t * NA;
    for (int e = lane; e < DH * DH; e += 64)
      Al[e + (e >> 5)] = At[e];
    __syncthreads();
    for (int j = 0; j < 16; j++) {
      int jj = half * 16 + j;
      float acc = 0.0f;
#pragma unroll
      for (int k = 0; k < 32; k++)
        acc += Al[i * 33 + k] * cur[k * 33 + jj];
      nxt[j] = acc;
    }
    __syncthreads();
    for (int j = 0; j < 16; j++) cur[i * 33 + half * 16 + j] = nxt[j];
    __syncthreads();
  }
  float* Pc = P + (size_t)bid * (DH * DH);
  for (int j = 0; j < 16; j++)
    Pc[i * 32 + half * 16 + j] = cur[i * 33 + half * 16 + j];
}

// ---------------------------------------------------------------------------
// Phase 2 (per batch b): sequential scan over chunk products per head
// ---------------------------------------------------------------------------
__global__ __launch_bounds__(64) void mps_chunkscan(
    const float* __restrict__ P, const float* __restrict__ h0,
    float* __restrict__ hstart) {
  int hh = blockIdx.x;
  int lane = threadIdx.x, i = lane & 31;
  float hv = h0[hh * 32 + i];
  const float* Pb = P + (size_t)hh * NCHUNK * (DH * DH);
  for (int c = 0; c < NCHUNK; c++) {
    if (lane < 32) hstart[((size_t)hh * NCHUNK + c) * 32 + i] = hv;
    const float* Pr = Pb + (size_t)c * (DH * DH) + i * 32;
    float y = 0.0f;
#pragma unroll
    for (int k = 0; k < 32; k++) y += Pr[k] * __shfl(hv, k);
    float nn = y * y;
#pragma unroll
    for (int o = 16; o; o >>= 1) nn += __shfl_xor(nn, o);
    hv = y / (sqrtf(nn) + 1e-6f);
  }
}

// ---------------------------------------------------------------------------
// Phase 3 (per batch b): replay 16 steps per chunk from hstart, fp32 A in
// ---------------------------------------------------------------------------
__global__ __launch_bounds__(64) void mps_expand_f32(
    const float* __restrict__ A, const float* __restrict__ hstart,
    __bf16* __restrict__ ys, int tok0base) {
  int bid = blockIdx.x;                    // hh*128 + c
  int c = bid & 127, hh = bid >> 7;
  int lane = threadIdx.x, i = lane & 31;
  float hv = hstart[(size_t)bid * 32 + i];
  for (int t = 0; t < CHUNK; t++) {
    int ltok = c * CHUNK + t;
    const float* Ar = A + (size_t)ltok * NA + (size_t)hh * (DH * DH) + i * 32;
    float y = 0.0f;
#pragma unroll
    for (int k = 0; k < 32; k++) y += Ar[k] * __shfl(hv, k);
    float nn = y * y;
#pragma unroll
    for (int o = 16; o; o >>= 1) nn += __shfl_xor(nn, o);
    hv = y / (sqrtf(nn) + 1e-6f);
    if (lane < 32)
      ys[(size_t)(tok0base + ltok) * (NH * DH) + hh * 32 + i] = (__bf16)hv;
  }
}

// ---------------------------------------------------------------------------
extern "C" void kernel_launch(void* const* d_in, const int* in_sizes, int n_in,
                              void* d_out, int out_size, void* d_ws, size_t ws_size,
                              hipStream_t stream) {
  const float* x     = (const float*)d_in[0];
  const float* ln1_g = (const float*)d_in[1];
  const float* ln1_b = (const float*)d_in[2];
  const float* Wa    = (const float*)d_in[3];
  const float* ba    = (const float*)d_in[4];
  const float* h0    = (const float*)d_in[5];
  const float* Wo    = (const float*)d_in[6];
  const float* bo    = (const float*)d_in[7];
  const float* ln2_g = (const float*)d_in[8];
  const float* ln2_b = (const float*)d_in[9];
  const float* W1    = (const float*)d_in[10];
  const float* b1    = (const float*)d_in[11];
  const float* W2    = (const float*)d_in[12];
  const float* b2    = (const float*)d_in[13];
  float* out = (float*)d_out;

  // Peak ws = 120.6 MB (r4 proved >=181 MB works). mid aliases Af32+P.
  char* wsb = (char*)d_ws;
  size_t off = 0;
  auto alloc = [&](size_t bytes) -> void* {
    void* p = wsb + off;
    off += (bytes + 255) & ~(size_t)255;
    return p;
  };
  __bf16* WoT  = (__bf16*)alloc((size_t)(NH * DH) * D_MODEL * 2);  // 0.5 MB
  __bf16* W1T  = (__bf16*)alloc((size_t)D_MODEL * D_FF * 2);       // 8 MB
  __bf16* W2T  = (__bf16*)alloc((size_t)D_FF * D_MODEL * 2);       // 8 MB
  __bf16* ys   = (__bf16*)alloc((size_t)NTOK * NH * DH * 2);       // 4 MB
  float*  hst  = (float*) alloc((size_t)NH * NCHUNK * DH * 4);     // 128 KB
  float*  xn32 = (float*) alloc((size_t)NTOK * D_MODEL * 4);       // 32 MB (LN1 fp32)
  __bf16* xnb  = (__bf16*)xn32;   // LN2 bf16 out reuses (xn32 dead by then)
  size_t tail0 = off;
  float*  Af32 = (float*) alloc((size_t)S_LEN * NA * 4);           // 64 MB (per-b)
  float*  P    = (float*) alloc((size_t)NH * NCHUNK * DH * DH * 4); // 4 MB (per-b)
  __bf16* mid  = (__bf16*)(wsb + tail0);  // 64 MB, aliases Af32+P

  // 1) FFN/Wo weights -> transposed bf16 (Wa used natively in fp32)
  transpose_bf16<<<dim3(D_MODEL / 32, (NH * DH) / 32), 256, 0, stream>>>(Wo, WoT, NH * DH, D_MODEL);
  transpose_bf16<<<dim3(D_FF / 32, D_MODEL / 32), 256, 0, stream>>>(W1, W1T, D_MODEL, D_FF);
  transpose_bf16<<<dim3(D_MODEL / 32, D_FF / 32), 256, 0, stream>>>(W2, W2T, D_FF, D_MODEL);

  // 2) LN1 -> fp32
  ln_kernel<1><<<NTOK, 256, 0, stream>>>(x, ln1_g, ln1_b, xn32);

  // 3) per-batch: fp32 A-GEMM + fp32 chunk recurrence
  for (int b = 0; b < BATCH; b++) {
    gemm_f32_f32out<<<dim3(NA / 64, S_LEN / 64), 256, 0, stream>>>(
        xn32 + (size_t)b * S_LEN * D_MODEL, Wa, ba, Af32, S_LEN, NA, D_MODEL);
    mps_chunkprod_f32<<<NH * NCHUNK, 64, 0, stream>>>(Af32, P);
    mps_chunkscan<<<NH, 64, 0, stream>>>(P, h0, hst);
    mps_expand_f32<<<NH * NCHUNK, 64, 0, stream>>>(Af32, hst, ys, b * S_LEN);
  }

  // 4) x2 = x + ys @ Wo + bo   -> d_out (fp32)
  gemm_bf16<EPI_F32_BIAS_RES><<<dim3(D_MODEL / 128, NTOK / 128), 256, 0, stream>>>(
      ys, WoT, bo, x, out, NTOK, D_MODEL, NH * DH);

  // 5) LN2 -> bf16
  ln_kernel<0><<<NTOK, 256, 0, stream>>>(out, ln2_g, ln2_b, xnb);

  // 6) mid = gelu(ln2 @ W1 + b1)
  gemm_bf16<EPI_BF16_BIAS_GELU><<<dim3(D_FF / 128, NTOK / 128), 256, 0, stream>>>(
      xnb, W1T, b1, nullptr, mid, NTOK, D_FF, D_MODEL);

  // 7) out = x2 + mid @ W2 + b2
  gemm_bf16<EPI_F32_BIAS_RES><<<dim3(D_MODEL / 128, NTOK / 128), 256, 0, stream>>>(
      mid, W2T, b2, out, out, NTOK, D_MODEL, D_FF);
}

// Round 7
// 1702.683 us; speedup vs baseline: 2.2329x; 2.2329x over previous
//
#include <hip/hip_runtime.h>
#include <hip/hip_bf16.h>
#include <math.h>

typedef float f32x4 __attribute__((ext_vector_type(4)));
typedef __bf16 bf16x4 __attribute__((ext_vector_type(4)));
typedef __bf16 bf16x8 __attribute__((ext_vector_type(8)));

#define AS1(p) ((const __attribute__((address_space(1))) void*)(p))
#define AS3(p) ((__attribute__((address_space(3))) void*)(p))

static constexpr int D_MODEL = 1024;
static constexpr int S_LEN   = 2048;
static constexpr int BATCH   = 4;
static constexpr int NTOK    = BATCH * S_LEN;   // 8192
static constexpr int NH      = 8;
static constexpr int DH      = 32;
static constexpr int NA      = NH * DH * DH;    // 8192
static constexpr int D_FF    = 4096;
static constexpr int CHUNK   = 16;
static constexpr int NCHUNK  = S_LEN / CHUNK;   // 128

// ---------------------------------------------------------------------------
// Transpose fp32 [R][C] -> bf16 [C][R]
// ---------------------------------------------------------------------------
__global__ __launch_bounds__(256) void transpose_bf16(
    const float* __restrict__ in, __bf16* __restrict__ out, int R, int C) {
  __shared__ float tile[32][33];
  int tx = threadIdx.x & 31, ty = threadIdx.x >> 5;   // 32 x 8
  int c0 = blockIdx.x * 32, r0 = blockIdx.y * 32;
  for (int i = ty; i < 32; i += 8)
    tile[i][tx] = in[(size_t)(r0 + i) * C + c0 + tx];
  __syncthreads();
  for (int i = ty; i < 32; i += 8)
    out[(size_t)(c0 + i) * R + r0 + tx] = (__bf16)tile[tx][i];
}

// ---------------------------------------------------------------------------
// Transpose fp32 [R][C] -> SPLIT bf16 hi/lo [C][R]  (x = hi + lo, lo in bf16)
// ---------------------------------------------------------------------------
__global__ __launch_bounds__(256) void transpose_split(
    const float* __restrict__ in, __bf16* __restrict__ ohi,
    __bf16* __restrict__ olo, int R, int C) {
  __shared__ float tile[32][33];
  int tx = threadIdx.x & 31, ty = threadIdx.x >> 5;
  int c0 = blockIdx.x * 32, r0 = blockIdx.y * 32;
  for (int i = ty; i < 32; i += 8)
    tile[i][tx] = in[(size_t)(r0 + i) * C + c0 + tx];
  __syncthreads();
  for (int i = ty; i < 32; i += 8) {
    float v = tile[tx][i];
    __bf16 h = (__bf16)v;
    ohi[(size_t)(c0 + i) * R + r0 + tx] = h;
    olo[(size_t)(c0 + i) * R + r0 + tx] = (__bf16)(v - (float)h);
  }
}

// ---------------------------------------------------------------------------
// LayerNorm: fp32 in. F32OUT=1 -> fp32; =0 -> bf16; =2 -> split hi/lo bf16
// ---------------------------------------------------------------------------
template <int MODE>
__global__ __launch_bounds__(256) void ln_kernel(
    const float* __restrict__ in, const float* __restrict__ g,
    const float* __restrict__ bta, void* __restrict__ outv,
    void* __restrict__ outv2) {
  int row = blockIdx.x, tid = threadIdx.x;
  const float4* in4 = (const float4*)(in + (size_t)row * D_MODEL);
  float4 v = in4[tid];
  float s  = v.x + v.y + v.z + v.w;
  float ss = v.x * v.x + v.y * v.y + v.z * v.z + v.w * v.w;
  for (int o = 32; o; o >>= 1) { s += __shfl_down(s, o); ss += __shfl_down(ss, o); }
  __shared__ float ps[4], pq[4];
  int lane = tid & 63, w = tid >> 6;
  if (lane == 0) { ps[w] = s; pq[w] = ss; }
  __syncthreads();
  s  = ps[0] + ps[1] + ps[2] + ps[3];
  ss = pq[0] + pq[1] + pq[2] + pq[3];
  float mean = s * (1.0f / D_MODEL);
  float var  = ss * (1.0f / D_MODEL) - mean * mean;
  float inv  = rsqrtf(fmaxf(var, 0.0f) + 1e-5f);
  float4 gv = ((const float4*)g)[tid];
  float4 bv = ((const float4*)bta)[tid];
  float o0 = (v.x - mean) * inv * gv.x + bv.x;
  float o1 = (v.y - mean) * inv * gv.y + bv.y;
  float o2 = (v.z - mean) * inv * gv.z + bv.z;
  float o3 = (v.w - mean) * inv * gv.w + bv.w;
  if (MODE == 1) {
    float4 o = {o0, o1, o2, o3};
    ((float4*)outv)[(size_t)row * (D_MODEL / 4) + tid] = o;
  } else if (MODE == 0) {
    bf16x4 o;
    o[0] = (__bf16)o0; o[1] = (__bf16)o1; o[2] = (__bf16)o2; o[3] = (__bf16)o3;
    ((bf16x4*)outv)[(size_t)row * (D_MODEL / 4) + tid] = o;
  } else {
    bf16x4 oh, ol;
    oh[0] = (__bf16)o0; oh[1] = (__bf16)o1; oh[2] = (__bf16)o2; oh[3] = (__bf16)o3;
    ol[0] = (__bf16)(o0 - (float)oh[0]);
    ol[1] = (__bf16)(o1 - (float)oh[1]);
    ol[2] = (__bf16)(o2 - (float)oh[2]);
    ol[3] = (__bf16)(o3 - (float)oh[3]);
    ((bf16x4*)outv )[(size_t)row * (D_MODEL / 4) + tid] = oh;
    ((bf16x4*)outv2)[(size_t)row * (D_MODEL / 4) + tid] = ol;
  }
}

// ---------------------------------------------------------------------------
// SPLIT-bf16 MFMA GEMM (fp32-accurate): C = (Ahi+Alo)(Bhi+Blo)^T + bias
//   ≈ Ahi·Bhi + Ahi·Blo + Alo·Bhi  (lo·lo dropped, ~eps^2 rel err)
// m97 structure, 128x128 tile, BK=32, fp32 out.
// ---------------------------------------------------------------------------
__global__ __launch_bounds__(256) void gemm_split_f32out(
    const __bf16* __restrict__ Ahi, const __bf16* __restrict__ Alo,
    const __bf16* __restrict__ BThi, const __bf16* __restrict__ BTlo,
    const float* __restrict__ bias, float* __restrict__ out,
    int M, int N, int K) {
  __shared__ __bf16 Ash[128 * 32], Asl[128 * 32];
  __shared__ __bf16 Bsh[128 * 32], Bsl[128 * 32];
  const int tid = threadIdx.x;
  const int lane = tid & 63, w = tid >> 6;
  const int m0 = blockIdx.y * 128, n0 = blockIdx.x * 128;
  const int wm = (w >> 1) * 64, wn = (w & 1) * 64;

  f32x4 acc[4][4];
#pragma unroll
  for (int a = 0; a < 4; a++)
#pragma unroll
    for (int b = 0; b < 4; b++)
#pragma unroll
      for (int r = 0; r < 4; r++) acc[a][b][r] = 0.0f;

  const int srow = tid >> 2;
  const int soff = (tid & 3) * 16;
  const size_t goff0 = (size_t)(m0 + srow) * K + (soff >> 1);
  const size_t goff1 = (size_t)(m0 + srow + 64) * K + (soff >> 1);
  const size_t hoff0 = (size_t)(n0 + srow) * K + (soff >> 1);
  const size_t hoff1 = (size_t)(n0 + srow + 64) * K + (soff >> 1);
  const int l0 = srow * 64 + soff, l1 = (srow + 64) * 64 + soff;

  const int fm = lane & 15, fq = lane >> 4;
  for (int k0 = 0; k0 < K; k0 += 32) {
    __builtin_amdgcn_global_load_lds(AS1(Ahi + goff0 + k0), AS3((char*)Ash + l0), 16, 0, 0);
    __builtin_amdgcn_global_load_lds(AS1(Ahi + goff1 + k0), AS3((char*)Ash + l1), 16, 0, 0);
    __builtin_amdgcn_global_load_lds(AS1(Alo + goff0 + k0), AS3((char*)Asl + l0), 16, 0, 0);
    __builtin_amdgcn_global_load_lds(AS1(Alo + goff1 + k0), AS3((char*)Asl + l1), 16, 0, 0);
    __builtin_amdgcn_global_load_lds(AS1(BThi + hoff0 + k0), AS3((char*)Bsh + l0), 16, 0, 0);
    __builtin_amdgcn_global_load_lds(AS1(BThi + hoff1 + k0), AS3((char*)Bsh + l1), 16, 0, 0);
    __builtin_amdgcn_global_load_lds(AS1(BTlo + hoff0 + k0), AS3((char*)Bsl + l0), 16, 0, 0);
    __builtin_amdgcn_global_load_lds(AS1(BTlo + hoff1 + k0), AS3((char*)Bsl + l1), 16, 0, 0);
    __syncthreads();
    bf16x8 ah[4], al[4], bh[4], bl[4];
#pragma unroll
    for (int t = 0; t < 4; t++) {
      int o = (wm + t * 16 + fm) * 64 + fq * 16;
      ah[t] = *(const bf16x8*)((const char*)Ash + o);
      al[t] = *(const bf16x8*)((const char*)Asl + o);
    }
#pragma unroll
    for (int t = 0; t < 4; t++) {
      int o = (wn + t * 16 + fm) * 64 + fq * 16;
      bh[t] = *(const bf16x8*)((const char*)Bsh + o);
      bl[t] = *(const bf16x8*)((const char*)Bsl + o);
    }
#pragma unroll
    for (int tm = 0; tm < 4; tm++)
#pragma unroll
      for (int tn = 0; tn < 4; tn++) {
        acc[tm][tn] = __builtin_amdgcn_mfma_f32_16x16x32_bf16(ah[tm], bh[tn], acc[tm][tn], 0, 0, 0);
        acc[tm][tn] = __builtin_amdgcn_mfma_f32_16x16x32_bf16(ah[tm], bl[tn], acc[tm][tn], 0, 0, 0);
        acc[tm][tn] = __builtin_amdgcn_mfma_f32_16x16x32_bf16(al[tm], bh[tn], acc[tm][tn], 0, 0, 0);
      }
    __syncthreads();
  }

#pragma unroll
  for (int tn = 0; tn < 4; tn++) {
    int col = n0 + wn + tn * 16 + fm;
    float bv = bias[col];
#pragma unroll
    for (int tm = 0; tm < 4; tm++) {
#pragma unroll
      for (int r = 0; r < 4; r++) {
        int row = m0 + wm + tm * 16 + fq * 4 + r;
        out[(size_t)row * N + col] = acc[tm][tn][r] + bv;
      }
    }
  }
}

// ---------------------------------------------------------------------------
// bf16 MFMA GEMM, m97 structure (known-good for Wo/FFN)
// ---------------------------------------------------------------------------
enum { EPI_BF16_BIAS = 0, EPI_BF16_BIAS_GELU = 1, EPI_F32_BIAS_RES = 2 };

template <int EPI>
__global__ __launch_bounds__(256) void gemm_bf16(
    const __bf16* __restrict__ Amat, const __bf16* __restrict__ BT,
    const float* __restrict__ bias, const float* __restrict__ res,
    void* __restrict__ out, int M, int N, int K) {
  __shared__ __bf16 As[128 * 32];
  __shared__ __bf16 Bs[128 * 32];
  const int tid = threadIdx.x;
  const int lane = tid & 63, w = tid >> 6;
  const int m0 = blockIdx.y * 128, n0 = blockIdx.x * 128;
  const int wm = (w >> 1) * 64, wn = (w & 1) * 64;

  f32x4 acc[4][4];
#pragma unroll
  for (int a = 0; a < 4; a++)
#pragma unroll
    for (int b = 0; b < 4; b++)
#pragma unroll
      for (int r = 0; r < 4; r++) acc[a][b][r] = 0.0f;

  const int srow = tid >> 2;
  const int soff = (tid & 3) * 16;
  const __bf16* gA0 = Amat + (size_t)(m0 + srow) * K + (soff >> 1);
  const __bf16* gA1 = Amat + (size_t)(m0 + srow + 64) * K + (soff >> 1);
  const __bf16* gB0 = BT + (size_t)(n0 + srow) * K + (soff >> 1);
  const __bf16* gB1 = BT + (size_t)(n0 + srow + 64) * K + (soff >> 1);
  char* lA0 = (char*)As + srow * 64 + soff;
  char* lA1 = (char*)As + (srow + 64) * 64 + soff;
  char* lB0 = (char*)Bs + srow * 64 + soff;
  char* lB1 = (char*)Bs + (srow + 64) * 64 + soff;

  const int fm = lane & 15, fq = lane >> 4;
  for (int k0 = 0; k0 < K; k0 += 32) {
    __builtin_amdgcn_global_load_lds(AS1(gA0 + k0), AS3(lA0), 16, 0, 0);
    __builtin_amdgcn_global_load_lds(AS1(gA1 + k0), AS3(lA1), 16, 0, 0);
    __builtin_amdgcn_global_load_lds(AS1(gB0 + k0), AS3(lB0), 16, 0, 0);
    __builtin_amdgcn_global_load_lds(AS1(gB1 + k0), AS3(lB1), 16, 0, 0);
    __syncthreads();
    bf16x8 af[4], bf[4];
#pragma unroll
    for (int t = 0; t < 4; t++)
      af[t] = *(const bf16x8*)((const char*)As + (wm + t * 16 + fm) * 64 + fq * 16);
#pragma unroll
    for (int t = 0; t < 4; t++)
      bf[t] = *(const bf16x8*)((const char*)Bs + (wn + t * 16 + fm) * 64 + fq * 16);
#pragma unroll
    for (int tm = 0; tm < 4; tm++)
#pragma unroll
      for (int tn = 0; tn < 4; tn++)
        acc[tm][tn] = __builtin_amdgcn_mfma_f32_16x16x32_bf16(af[tm], bf[tn], acc[tm][tn], 0, 0, 0);
    __syncthreads();
  }

#pragma unroll
  for (int tn = 0; tn < 4; tn++) {
    int col = n0 + wn + tn * 16 + fm;
    float bv = bias[col];
#pragma unroll
    for (int tm = 0; tm < 4; tm++) {
#pragma unroll
      for (int r = 0; r < 4; r++) {
        int row = m0 + wm + tm * 16 + fq * 4 + r;
        float v = acc[tm][tn][r] + bv;
        size_t idx = (size_t)row * N + col;
        if (EPI == EPI_F32_BIAS_RES) {
          ((float*)out)[idx] = v + res[idx];
        } else if (EPI == EPI_BF16_BIAS_GELU) {
          v = 0.5f * v * (1.0f + erff(v * 0.70710678118654752f));
          ((__bf16*)out)[idx] = (__bf16)v;
        } else {
          ((__bf16*)out)[idx] = (__bf16)v;
        }
      }
    }
  }
}

// ---------------------------------------------------------------------------
// Phase 1 (per batch b): chunk product P = A_{s0+15}...A_{s0}, fp32
// ---------------------------------------------------------------------------
__global__ __launch_bounds__(64) void mps_chunkprod_f32(
    const float* __restrict__ A, float* __restrict__ P) {
  int bid = blockIdx.x;            // hh*128 + c
  int c = bid & 127, hh = bid >> 7;
  int lane = threadIdx.x;
  int i = lane & 31, half = lane >> 5;
  __shared__ float Al[32 * 33];
  __shared__ float cur[32 * 33];

  for (int j = 0; j < 16; j++)
    cur[i * 33 + half * 16 + j] = (i == half * 16 + j) ? 1.0f : 0.0f;
  __syncthreads();

  const float* Abase = A + (size_t)(c * CHUNK) * NA + (size_t)hh * (DH * DH);
  float nxt[16];
  for (int t = 0; t < CHUNK; t++) {
    const float* At = Abase + (size_t)t * NA;
    for (int e = lane; e < DH * DH; e += 64)
      Al[e + (e >> 5)] = At[e];
    __syncthreads();
    for (int j = 0; j < 16; j++) {
      int jj = half * 16 + j;
      float acc = 0.0f;
#pragma unroll
      for (int k = 0; k < 32; k++)
        acc += Al[i * 33 + k] * cur[k * 33 + jj];
      nxt[j] = acc;
    }
    __syncthreads();
    for (int j = 0; j < 16; j++) cur[i * 33 + half * 16 + j] = nxt[j];
    __syncthreads();
  }
  float* Pc = P + (size_t)bid * (DH * DH);
  for (int j = 0; j < 16; j++)
    Pc[i * 32 + half * 16 + j] = cur[i * 33 + half * 16 + j];
}

// ---------------------------------------------------------------------------
// Phase 2 (per batch b): sequential scan over chunk products per head
// ---------------------------------------------------------------------------
__global__ __launch_bounds__(64) void mps_chunkscan(
    const float* __restrict__ P, const float* __restrict__ h0,
    float* __restrict__ hstart) {
  int hh = blockIdx.x;
  int lane = threadIdx.x, i = lane & 31;
  float hv = h0[hh * 32 + i];
  const float* Pb = P + (size_t)hh * NCHUNK * (DH * DH);
  for (int c = 0; c < NCHUNK; c++) {
    if (lane < 32) hstart[((size_t)hh * NCHUNK + c) * 32 + i] = hv;
    const float* Pr = Pb + (size_t)c * (DH * DH) + i * 32;
    float y = 0.0f;
#pragma unroll
    for (int k = 0; k < 32; k++) y += Pr[k] * __shfl(hv, k);
    float nn = y * y;
#pragma unroll
    for (int o = 16; o; o >>= 1) nn += __shfl_xor(nn, o);
    hv = y / (sqrtf(nn) + 1e-6f);
  }
}

// ---------------------------------------------------------------------------
// Phase 3 (per batch b): replay 16 steps per chunk from hstart
// ---------------------------------------------------------------------------
__global__ __launch_bounds__(64) void mps_expand_f32(
    const float* __restrict__ A, const float* __restrict__ hstart,
    __bf16* __restrict__ ys, int tok0base) {
  int bid = blockIdx.x;                    // hh*128 + c
  int c = bid & 127, hh = bid >> 7;
  int lane = threadIdx.x, i = lane & 31;
  float hv = hstart[(size_t)bid * 32 + i];
  for (int t = 0; t < CHUNK; t++) {
    int ltok = c * CHUNK + t;
    const float* Ar = A + (size_t)ltok * NA + (size_t)hh * (DH * DH) + i * 32;
    float y = 0.0f;
#pragma unroll
    for (int k = 0; k < 32; k++) y += Ar[k] * __shfl(hv, k);
    float nn = y * y;
#pragma unroll
    for (int o = 16; o; o >>= 1) nn += __shfl_xor(nn, o);
    hv = y / (sqrtf(nn) + 1e-6f);
    if (lane < 32)
      ys[(size_t)(tok0base + ltok) * (NH * DH) + hh * 32 + i] = (__bf16)hv;
  }
}

// ---------------------------------------------------------------------------
extern "C" void kernel_launch(void* const* d_in, const int* in_sizes, int n_in,
                              void* d_out, int out_size, void* d_ws, size_t ws_size,
                              hipStream_t stream) {
  const float* x     = (const float*)d_in[0];
  const float* ln1_g = (const float*)d_in[1];
  const float* ln1_b = (const float*)d_in[2];
  const float* Wa    = (const float*)d_in[3];
  const float* ba    = (const float*)d_in[4];
  const float* h0    = (const float*)d_in[5];
  const float* Wo    = (const float*)d_in[6];
  const float* bo    = (const float*)d_in[7];
  const float* ln2_g = (const float*)d_in[8];
  const float* ln2_b = (const float*)d_in[9];
  const float* W1    = (const float*)d_in[10];
  const float* b1    = (const float*)d_in[11];
  const float* W2    = (const float*)d_in[12];
  const float* b2    = (const float*)d_in[13];
  float* out = (float*)d_out;

  // Peak ws = 152.6 MB (<181 MB proven). mid aliases Af32+P.
  char* wsb = (char*)d_ws;
  size_t off = 0;
  auto alloc = [&](size_t bytes) -> void* {
    void* p = wsb + off;
    off += (bytes + 255) & ~(size_t)255;
    return p;
  };
  __bf16* WoT   = (__bf16*)alloc((size_t)(NH * DH) * D_MODEL * 2);  // 0.5 MB
  __bf16* W1T   = (__bf16*)alloc((size_t)D_MODEL * D_FF * 2);       // 8 MB
  __bf16* W2T   = (__bf16*)alloc((size_t)D_FF * D_MODEL * 2);       // 8 MB
  __bf16* ys    = (__bf16*)alloc((size_t)NTOK * NH * DH * 2);       // 4 MB
  float*  hst   = (float*) alloc((size_t)NH * NCHUNK * DH * 4);     // 128 KB
  __bf16* xnh   = (__bf16*)alloc((size_t)NTOK * D_MODEL * 2);       // 16 MB (LN1 hi; later LN2 bf16)
  __bf16* xnl   = (__bf16*)alloc((size_t)NTOK * D_MODEL * 2);       // 16 MB (LN1 lo)
  __bf16* WaTh  = (__bf16*)alloc((size_t)D_MODEL * NA * 2);         // 16 MB
  __bf16* WaTl  = (__bf16*)alloc((size_t)D_MODEL * NA * 2);         // 16 MB
  size_t tail0 = off;
  float*  Af32 = (float*) alloc((size_t)S_LEN * NA * 4);            // 64 MB (per-b)
  float*  P    = (float*) alloc((size_t)NH * NCHUNK * DH * DH * 4); // 4 MB (per-b)
  __bf16* mid  = (__bf16*)(wsb + tail0);  // 64 MB, aliases Af32+P

  // 1) weights: Wo/W1/W2 -> bf16 transposed; Wa -> split hi/lo transposed
  transpose_bf16<<<dim3(D_MODEL / 32, (NH * DH) / 32), 256, 0, stream>>>(Wo, WoT, NH * DH, D_MODEL);
  transpose_bf16<<<dim3(D_FF / 32, D_MODEL / 32), 256, 0, stream>>>(W1, W1T, D_MODEL, D_FF);
  transpose_bf16<<<dim3(D_MODEL / 32, D_FF / 32), 256, 0, stream>>>(W2, W2T, D_FF, D_MODEL);
  transpose_split<<<dim3(NA / 32, D_MODEL / 32), 256, 0, stream>>>(Wa, WaTh, WaTl, D_MODEL, NA);

  // 2) LN1 -> split hi/lo bf16
  ln_kernel<2><<<NTOK, 256, 0, stream>>>(x, ln1_g, ln1_b, xnh, xnl);

  // 3) per-batch: split-MFMA A-GEMM (fp32-accurate) + fp32 chunk recurrence
  for (int b = 0; b < BATCH; b++) {
    gemm_split_f32out<<<dim3(NA / 128, S_LEN / 128), 256, 0, stream>>>(
        xnh + (size_t)b * S_LEN * D_MODEL, xnl + (size_t)b * S_LEN * D_MODEL,
        WaTh, WaTl, ba, Af32, S_LEN, NA, D_MODEL);
    mps_chunkprod_f32<<<NH * NCHUNK, 64, 0, stream>>>(Af32, P);
    mps_chunkscan<<<NH, 64, 0, stream>>>(P, h0, hst);
    mps_expand_f32<<<NH * NCHUNK, 64, 0, stream>>>(Af32, hst, ys, b * S_LEN);
  }

  // 4) x2 = x + ys @ Wo + bo   -> d_out (fp32)
  gemm_bf16<EPI_F32_BIAS_RES><<<dim3(D_MODEL / 128, NTOK / 128), 256, 0, stream>>>(
      ys, WoT, bo, x, out, NTOK, D_MODEL, NH * DH);

  // 5) LN2 -> bf16 (reuses xnh region; xnh/xnl dead after step 3)
  ln_kernel<0><<<NTOK, 256, 0, stream>>>(out, ln2_g, ln2_b, xnh, nullptr);

  // 6) mid = gelu(ln2 @ W1 + b1)
  gemm_bf16<EPI_BF16_BIAS_GELU><<<dim3(D_FF / 128, NTOK / 128), 256, 0, stream>>>(
      xnh, W1T, b1, nullptr, mid, NTOK, D_FF, D_MODEL);

  // 7) out = x2 + mid @ W2 + b2
  gemm_bf16<EPI_F32_BIAS_RES><<<dim3(D_MODEL / 128, NTOK / 128), 256, 0, stream>>>(
      mid, W2T, b2, out, out, NTOK, D_MODEL, D_FF);
}